// Round 1
// baseline (1165.066 us; speedup 1.0000x reference)
//
#include <hip/hip_runtime.h>
#include <hip/hip_bf16.h>
#include <math.h>

// Problem constants (fixed by the reference)
#define L_SEQ   16384
#define DMODEL  1024
#define DSTATE  512
#define CHUNK   128
#define NCHUNK  (L_SEQ / CHUNK)   // 128

// ---------------- setup: lambda, lambda^CHUNK, gamma ----------------
__global__ void setup_params(const float* __restrict__ nu_log,
                             const float* __restrict__ theta_log,
                             const float* __restrict__ gamma_log,
                             float* __restrict__ lr, float* __restrict__ li,
                             float* __restrict__ lTr, float* __restrict__ lTi,
                             float* __restrict__ gam) {
    int s = threadIdx.x;
    if (s >= DSTATE) return;
    float mod = expf(-expf(nu_log[s]));
    float th  = expf(theta_log[s]);
    float ar = mod * cosf(th);
    float ai = mod * sinf(th);
    lr[s] = ar; li[s] = ai;
    gam[s] = expf(gamma_log[s]);
    float tr = 1.f, ti = 0.f;
    for (int i = 0; i < CHUNK; ++i) {
        float nr = tr * ar - ti * ai;
        float ni = tr * ai + ti * ar;
        tr = nr; ti = ni;
    }
    lTr[s] = tr; lTi[s] = ti;
}

// ---------------- GEMM1: Bu = x @ (B*gamma)^T, re+im fused ----------------
// A: X [M x K] row-major, B: Bre/Bim [N x K] row-major (dot over K)
#define BM 64
#define BN 64
#define BK 16

__global__ __launch_bounds__(256)
void gemm1(const float* __restrict__ X,
           const float* __restrict__ Bre, const float* __restrict__ Bim,
           const float* __restrict__ gam,
           float* __restrict__ BuR, float* __restrict__ BuI,
           int M, int N, int K) {
    __shared__ float As[BK][BM + 1];
    __shared__ float Bsr[BK][BN + 1];
    __shared__ float Bsi[BK][BN + 1];

    const int tid = threadIdx.x;
    const int tx = tid & 15, ty = tid >> 4;
    const int m0 = blockIdx.x * BM, n0 = blockIdx.y * BN;

    float accR[4][4] = {{0.f}}, accI[4][4] = {{0.f}};

    const int kk  = tid & 15;     // 0..15 within k-tile
    const int row = tid >> 4;     // 0..15

    for (int k0 = 0; k0 < K; k0 += BK) {
        #pragma unroll
        for (int i = 0; i < 4; ++i) {
            int m = row + i * 16;
            As [kk][m] = X  [(size_t)(m0 + m) * K + k0 + kk];
            Bsr[kk][m] = Bre[(size_t)(n0 + m) * K + k0 + kk];
            Bsi[kk][m] = Bim[(size_t)(n0 + m) * K + k0 + kk];
        }
        __syncthreads();
        #pragma unroll
        for (int k = 0; k < BK; ++k) {
            float a[4], br[4], bi[4];
            #pragma unroll
            for (int i = 0; i < 4; ++i) a[i]  = As [k][ty + 16 * i];
            #pragma unroll
            for (int j = 0; j < 4; ++j) { br[j] = Bsr[k][tx + 16 * j]; bi[j] = Bsi[k][tx + 16 * j]; }
            #pragma unroll
            for (int i = 0; i < 4; ++i)
                #pragma unroll
                for (int j = 0; j < 4; ++j) {
                    accR[i][j] = fmaf(a[i], br[j], accR[i][j]);
                    accI[i][j] = fmaf(a[i], bi[j], accI[i][j]);
                }
        }
        __syncthreads();
    }

    #pragma unroll
    for (int i = 0; i < 4; ++i)
        #pragma unroll
        for (int j = 0; j < 4; ++j) {
            int m = m0 + ty + 16 * i;
            int n = n0 + tx + 16 * j;
            float g = gam[n];
            BuR[(size_t)m * N + n] = accR[i][j] * g;
            BuI[(size_t)m * N + n] = accI[i][j] * g;
        }
}

// ---------------- scan pass 1: local scans per chunk ----------------
__global__ __launch_bounds__(DSTATE)
void scan_local(float* __restrict__ BuR, float* __restrict__ BuI,
                const float* __restrict__ lr_, const float* __restrict__ li_,
                float* __restrict__ endR, float* __restrict__ endI) {
    int s = threadIdx.x;
    int c = blockIdx.x;
    float lr = lr_[s], li = li_[s];
    float hr = 0.f, hi = 0.f;
    size_t base = (size_t)c * CHUNK * DSTATE + s;
    for (int t = 0; t < CHUNK; ++t) {
        float br = BuR[base + (size_t)t * DSTATE];
        float bi = BuI[base + (size_t)t * DSTATE];
        float nr = fmaf(lr, hr, fmaf(-li, hi, br));
        float ni = fmaf(lr, hi, fmaf( li, hr, bi));
        hr = nr; hi = ni;
        BuR[base + (size_t)t * DSTATE] = hr;
        BuI[base + (size_t)t * DSTATE] = hi;
    }
    endR[c * DSTATE + s] = hr;
    endI[c * DSTATE + s] = hi;
}

// ---------------- scan pass 2: carries across chunks ----------------
__global__ __launch_bounds__(DSTATE)
void scan_carry(const float* __restrict__ endR, const float* __restrict__ endI,
                const float* __restrict__ lTr_, const float* __restrict__ lTi_,
                float* __restrict__ carR, float* __restrict__ carI) {
    int s = threadIdx.x;
    float ar = lTr_[s], ai = lTi_[s];
    float cr = 0.f, ci = 0.f;
    for (int c = 0; c < NCHUNK; ++c) {
        carR[c * DSTATE + s] = cr;
        carI[c * DSTATE + s] = ci;
        float er = endR[c * DSTATE + s];
        float ei = endI[c * DSTATE + s];
        float nr = fmaf(ar, cr, fmaf(-ai, ci, er));
        float ni = fmaf(ar, ci, fmaf( ai, cr, ei));
        cr = nr; ci = ni;
    }
}

// ---------------- scan pass 3: apply carries ----------------
__global__ __launch_bounds__(DSTATE)
void scan_apply(float* __restrict__ BuR, float* __restrict__ BuI,
                const float* __restrict__ lr_, const float* __restrict__ li_,
                const float* __restrict__ carR, const float* __restrict__ carI) {
    int s = threadIdx.x;
    int c = blockIdx.x;
    if (c == 0) return;  // carry is zero
    float lr = lr_[s], li = li_[s];
    float pr = carR[c * DSTATE + s];
    float pi = carI[c * DSTATE + s];
    if (pr == 0.f && pi == 0.f) return;
    size_t base = (size_t)c * CHUNK * DSTATE + s;
    for (int t = 0; t < CHUNK; ++t) {
        float nr = lr * pr - li * pi;
        float ni = lr * pi + li * pr;
        pr = nr; pi = ni;
        BuR[base + (size_t)t * DSTATE] += pr;
        BuI[base + (size_t)t * DSTATE] += pi;
    }
}

// ---------------- GEMM2: y = Hr@Cre^T - Hi@Cim^T + D*x ----------------
__global__ __launch_bounds__(256)
void gemm2(const float* __restrict__ Hr, const float* __restrict__ Hi,
           const float* __restrict__ Cre, const float* __restrict__ Cim,
           const float* __restrict__ Dv, const float* __restrict__ X,
           float* __restrict__ Y, int M, int N, int K) {
    __shared__ float Asr[BK][BM + 1];
    __shared__ float Asi[BK][BM + 1];
    __shared__ float Bsr[BK][BN + 1];
    __shared__ float Bsi[BK][BN + 1];

    const int tid = threadIdx.x;
    const int tx = tid & 15, ty = tid >> 4;
    const int m0 = blockIdx.x * BM, n0 = blockIdx.y * BN;

    float acc[4][4] = {{0.f}};

    const int kk  = tid & 15;
    const int row = tid >> 4;

    for (int k0 = 0; k0 < K; k0 += BK) {
        #pragma unroll
        for (int i = 0; i < 4; ++i) {
            int m = row + i * 16;
            Asr[kk][m] = Hr [(size_t)(m0 + m) * K + k0 + kk];
            Asi[kk][m] = Hi [(size_t)(m0 + m) * K + k0 + kk];
            Bsr[kk][m] = Cre[(size_t)(n0 + m) * K + k0 + kk];
            Bsi[kk][m] = Cim[(size_t)(n0 + m) * K + k0 + kk];
        }
        __syncthreads();
        #pragma unroll
        for (int k = 0; k < BK; ++k) {
            float ar[4], ai[4], br[4], bi[4];
            #pragma unroll
            for (int i = 0; i < 4; ++i) { ar[i] = Asr[k][ty + 16 * i]; ai[i] = Asi[k][ty + 16 * i]; }
            #pragma unroll
            for (int j = 0; j < 4; ++j) { br[j] = Bsr[k][tx + 16 * j]; bi[j] = Bsi[k][tx + 16 * j]; }
            #pragma unroll
            for (int i = 0; i < 4; ++i)
                #pragma unroll
                for (int j = 0; j < 4; ++j) {
                    acc[i][j] = fmaf(ar[i], br[j], acc[i][j]);
                    acc[i][j] = fmaf(-ai[i], bi[j], acc[i][j]);
                }
        }
        __syncthreads();
    }

    #pragma unroll
    for (int i = 0; i < 4; ++i)
        #pragma unroll
        for (int j = 0; j < 4; ++j) {
            int m = m0 + ty + 16 * i;
            int n = n0 + tx + 16 * j;
            Y[(size_t)m * N + n] = acc[i][j] + Dv[n] * X[(size_t)m * N + n];
        }
}

extern "C" void kernel_launch(void* const* d_in, const int* in_sizes, int n_in,
                              void* d_out, int out_size, void* d_ws, size_t ws_size,
                              hipStream_t stream) {
    const float* X         = (const float*)d_in[0];
    const float* nu_log    = (const float*)d_in[1];
    const float* theta_log = (const float*)d_in[2];
    const float* gamma_log = (const float*)d_in[3];
    const float* Bre       = (const float*)d_in[4];
    const float* Bim       = (const float*)d_in[5];
    const float* Cre       = (const float*)d_in[6];
    const float* Cim       = (const float*)d_in[7];
    const float* Dv        = (const float*)d_in[8];
    float* Y = (float*)d_out;

    // workspace layout (floats)
    char* ws = (char*)d_ws;
    size_t off = 0;
    float* BuR  = (float*)(ws + off); off += (size_t)L_SEQ * DSTATE * 4;
    float* BuI  = (float*)(ws + off); off += (size_t)L_SEQ * DSTATE * 4;
    float* endR = (float*)(ws + off); off += (size_t)NCHUNK * DSTATE * 4;
    float* endI = (float*)(ws + off); off += (size_t)NCHUNK * DSTATE * 4;
    float* carR = (float*)(ws + off); off += (size_t)NCHUNK * DSTATE * 4;
    float* carI = (float*)(ws + off); off += (size_t)NCHUNK * DSTATE * 4;
    float* lr   = (float*)(ws + off); off += DSTATE * 4;
    float* li   = (float*)(ws + off); off += DSTATE * 4;
    float* lTr  = (float*)(ws + off); off += DSTATE * 4;
    float* lTi  = (float*)(ws + off); off += DSTATE * 4;
    float* gam  = (float*)(ws + off); off += DSTATE * 4;

    setup_params<<<1, DSTATE, 0, stream>>>(nu_log, theta_log, gamma_log, lr, li, lTr, lTi, gam);

    dim3 g1(L_SEQ / BM, DSTATE / BN);       // 256 x 8
    gemm1<<<g1, 256, 0, stream>>>(X, Bre, Bim, gam, BuR, BuI, L_SEQ, DSTATE, DMODEL);

    scan_local<<<NCHUNK, DSTATE, 0, stream>>>(BuR, BuI, lr, li, endR, endI);
    scan_carry<<<1, DSTATE, 0, stream>>>(endR, endI, lTr, lTi, carR, carI);
    scan_apply<<<NCHUNK, DSTATE, 0, stream>>>(BuR, BuI, lr, li, carR, carI);

    dim3 g2(L_SEQ / BM, DMODEL / BN);       // 256 x 16
    gemm2<<<g2, 256, 0, stream>>>(BuR, BuI, Cre, Cim, Dv, X, Y, L_SEQ, DMODEL, DSTATE);
}

// Round 2
// 202.613 us; speedup vs baseline: 5.7502x; 5.7502x over previous
//
#include <hip/hip_runtime.h>
#include <hip/hip_bf16.h>
#include <math.h>

#define L_SEQ   16384
#define DMODEL  1024
#define DSTATE  512
#define CHUNK   64
#define NCHUNK  (L_SEQ / CHUNK)   // 256

typedef float  f32x4 __attribute__((ext_vector_type(4)));
typedef short  s16x8 __attribute__((ext_vector_type(8)));

__device__ __forceinline__ unsigned short f2bf(float f) {
    union { float f; unsigned int u; } v; v.f = f;
    unsigned int r = v.u + 0x7fffu + ((v.u >> 16) & 1u);   // RNE
    return (unsigned short)(r >> 16);
}

__device__ __forceinline__ void mfma16(f32x4& d, s16x8 a, s16x8 b) {
    asm volatile("v_mfma_f32_16x16x32_bf16 %0, %1, %2, %0"
                 : "+v"(d) : "v"(a), "v"(b));
}

// ---------------- setup: lambda, lambda^CHUNK ----------------
__global__ void setup_params(const float* __restrict__ nu_log,
                             const float* __restrict__ theta_log,
                             float* __restrict__ lam, float* __restrict__ lamT) {
    int s = threadIdx.x;
    if (s >= DSTATE) return;
    float mod = expf(-expf(nu_log[s]));
    float th  = expf(theta_log[s]);
    float ar = mod * cosf(th);
    float ai = mod * sinf(th);
    lam[s] = ar; lam[DSTATE + s] = ai;
    float pr = 1.f, pi = 0.f;
    for (int i = 0; i < CHUNK; ++i) {
        float nr = pr * ar - pi * ai;
        float ni = pr * ai + pi * ar;
        pr = nr; pi = ni;
    }
    lamT[s] = pr; lamT[DSTATE + s] = pi;
}

// ---------------- weight packing ----------------
// W1[n][k] = bf16( gamma[n&511] * (n<512 ? Bre[n][k] : Bim[n-512][k]) )
__global__ void pack_w1(const float* __restrict__ Bre, const float* __restrict__ Bim,
                        const float* __restrict__ gamma_log, unsigned short* __restrict__ W1) {
    int idx = blockIdx.x * 256 + threadIdx.x;        // 0 .. 1M-1
    int n = idx >> 10, k = idx & 1023;
    float g = expf(gamma_log[n & (DSTATE - 1)]);
    float v = (n < DSTATE) ? Bre[n * DMODEL + k] : Bim[(n - DSTATE) * DMODEL + k];
    W1[idx] = f2bf(v * g);
}

// W2[n][k] = bf16( k<512 ? Cre[n][k] : -Cim[n][k-512] )
__global__ void pack_w2(const float* __restrict__ Cre, const float* __restrict__ Cim,
                        unsigned short* __restrict__ W2) {
    int idx = blockIdx.x * 256 + threadIdx.x;
    int n = idx >> 10, k = idx & 1023;
    float v = (k < DSTATE) ? Cre[n * DSTATE + k] : -Cim[n * DSTATE + (k - DSTATE)];
    W2[idx] = f2bf(v);
}

// ---------------- X fp32 -> bf16 ----------------
__global__ void conv_x(const float4* __restrict__ X, ushort4* __restrict__ Xb) {
    int i = blockIdx.x * 256 + threadIdx.x;    // each handles 4 floats
    float4 v = X[i];
    ushort4 o;
    o.x = f2bf(v.x); o.y = f2bf(v.y); o.z = f2bf(v.z); o.w = f2bf(v.w);
    Xb[i] = o;
}

// ---------------- bf16 MFMA GEMM: C[M][1024] = A[M][1024] @ B[1024][1024]^T ----
// A,B bf16 row-major over K; C fp32. EPI: C += Dv[n]*Xf[m][n].
template<int EPI>
__global__ __launch_bounds__(256)
void gemm_bf16(const unsigned short* __restrict__ A, const unsigned short* __restrict__ B,
               float* __restrict__ C, const float* __restrict__ Dv,
               const float* __restrict__ Xf) {
    const int K = 1024, N = 1024;
    __shared__ __align__(16) unsigned short As[128 * 32];
    __shared__ __align__(16) unsigned short Bs[128 * 32];

    const int tid  = threadIdx.x;
    const int lane = tid & 63;
    const int wave = tid >> 6;            // 0..3
    const int wr   = wave >> 1, wc = wave & 1;   // 2x2 waves of 64x64
    const int m0 = blockIdx.y * 128;
    const int n0 = blockIdx.x * 128;

    const int srow = tid >> 2;            // 0..63
    const int skb  = (tid & 3) * 8;       // element offset of 16B chunk in K

    const unsigned short* Ag0 = A + (size_t)(m0 + srow) * K + skb;
    const unsigned short* Ag1 = Ag0 + (size_t)64 * K;
    const unsigned short* Bg0 = B + (size_t)(n0 + srow) * K + skb;
    const unsigned short* Bg1 = Bg0 + (size_t)64 * K;

    f32x4 acc[4][4] = {};

    // prefetch tile 0
    uint4 ra0 = *(const uint4*)Ag0;
    uint4 ra1 = *(const uint4*)Ag1;
    uint4 rb0 = *(const uint4*)Bg0;
    uint4 rb1 = *(const uint4*)Bg1;

    const int fr = lane & 15;             // row within 16x16 fragment
    const int fk = (lane >> 4) * 8;       // k-offset of this lane's 8 elems

    for (int k0 = 0; k0 < K; k0 += 32) {
        __syncthreads();                  // prev compute done reading LDS
        *(uint4*)&As[srow * 32 + skb]        = ra0;
        *(uint4*)&As[(64 + srow) * 32 + skb] = ra1;
        *(uint4*)&Bs[srow * 32 + skb]        = rb0;
        *(uint4*)&Bs[(64 + srow) * 32 + skb] = rb1;
        __syncthreads();
        if (k0 + 32 < K) {                // prefetch next tile (overlaps MFMA)
            ra0 = *(const uint4*)(Ag0 + k0 + 32);
            ra1 = *(const uint4*)(Ag1 + k0 + 32);
            rb0 = *(const uint4*)(Bg0 + k0 + 32);
            rb1 = *(const uint4*)(Bg1 + k0 + 32);
        }
        s16x8 af[4], bfq[4];
        #pragma unroll
        for (int i = 0; i < 4; ++i)
            af[i] = *(const s16x8*)&As[(wr * 64 + i * 16 + fr) * 32 + fk];
        #pragma unroll
        for (int j = 0; j < 4; ++j)
            bfq[j] = *(const s16x8*)&Bs[(wc * 64 + j * 16 + fr) * 32 + fk];
        #pragma unroll
        for (int i = 0; i < 4; ++i)
            #pragma unroll
            for (int j = 0; j < 4; ++j)
                mfma16(acc[i][j], af[i], bfq[j]);
    }

    const int crow = (lane >> 4) * 4;     // C/D: col=lane&15, row=(lane>>4)*4+r
    const int ccol = lane & 15;
    #pragma unroll
    for (int i = 0; i < 4; ++i) {
        #pragma unroll
        for (int j = 0; j < 4; ++j) {
            const int mbase = m0 + wr * 64 + i * 16 + crow;
            const int n     = n0 + wc * 64 + j * 16 + ccol;
            #pragma unroll
            for (int r = 0; r < 4; ++r) {
                const int m = mbase + r;
                float v = acc[i][j][r];
                if (EPI) v += Dv[n] * Xf[(size_t)m * N + n];
                C[(size_t)m * N + n] = v;
            }
        }
    }
}

// ---------------- scan: Bu fp32 (L,1024): real col s, imag col s+512 --------
__global__ __launch_bounds__(512)
void scan_local(float* __restrict__ Bu, const float* __restrict__ lam,
                float* __restrict__ endRI) {
    const int s = threadIdx.x;
    const int c = blockIdx.x;
    const float lr = lam[s], li = lam[DSTATE + s];
    size_t base = (size_t)c * CHUNK * 1024 + s;
    float hr = 0.f, hi = 0.f;
    #pragma unroll 4
    for (int t = 0; t < CHUNK; ++t) {
        float br = Bu[base + (size_t)t * 1024];
        float bi = Bu[base + (size_t)t * 1024 + DSTATE];
        float nr = fmaf(lr, hr, fmaf(-li, hi, br));
        float ni = fmaf(lr, hi, fmaf( li, hr, bi));
        hr = nr; hi = ni;
        Bu[base + (size_t)t * 1024]          = hr;
        Bu[base + (size_t)t * 1024 + DSTATE] = hi;
    }
    endRI[c * 1024 + s] = hr;
    endRI[c * 1024 + DSTATE + s] = hi;
}

__global__ __launch_bounds__(512)
void scan_carry(const float* __restrict__ endRI, const float* __restrict__ lamT,
                float* __restrict__ carRI) {
    const int s = threadIdx.x;
    const float ar = lamT[s], ai = lamT[DSTATE + s];
    float cr = 0.f, ci = 0.f;
    for (int c = 0; c < NCHUNK; ++c) {
        carRI[c * 1024 + s] = cr;
        carRI[c * 1024 + DSTATE + s] = ci;
        float er = endRI[c * 1024 + s];
        float ei = endRI[c * 1024 + DSTATE + s];
        float nr = fmaf(ar, cr, fmaf(-ai, ci, er));
        float ni = fmaf(ar, ci, fmaf( ai, cr, ei));
        cr = nr; ci = ni;
    }
}

__global__ __launch_bounds__(512)
void scan_apply(const float* __restrict__ Bu, const float* __restrict__ lam,
                const float* __restrict__ carRI, unsigned short* __restrict__ H) {
    const int s = threadIdx.x;
    const int c = blockIdx.x;
    const float lr = lam[s], li = lam[DSTATE + s];
    float pr = carRI[c * 1024 + s];
    float pi = carRI[c * 1024 + DSTATE + s];
    size_t base = (size_t)c * CHUNK * 1024 + s;
    #pragma unroll 4
    for (int t = 0; t < CHUNK; ++t) {
        float nr = lr * pr - li * pi;     // lambda^{t+1} * carry
        float ni = lr * pi + li * pr;
        pr = nr; pi = ni;
        float hr = Bu[base + (size_t)t * 1024] + pr;
        float hi = Bu[base + (size_t)t * 1024 + DSTATE] + pi;
        H[base + (size_t)t * 1024]          = f2bf(hr);
        H[base + (size_t)t * 1024 + DSTATE] = f2bf(hi);
    }
}

extern "C" void kernel_launch(void* const* d_in, const int* in_sizes, int n_in,
                              void* d_out, int out_size, void* d_ws, size_t ws_size,
                              hipStream_t stream) {
    const float* X         = (const float*)d_in[0];
    const float* nu_log    = (const float*)d_in[1];
    const float* theta_log = (const float*)d_in[2];
    const float* gamma_log = (const float*)d_in[3];
    const float* Bre       = (const float*)d_in[4];
    const float* Bim       = (const float*)d_in[5];
    const float* Cre       = (const float*)d_in[6];
    const float* Cim       = (const float*)d_in[7];
    const float* Dv        = (const float*)d_in[8];
    float* Y = (float*)d_out;

    // workspace (~40 MB). Bu fp32 lives in d_out (64 MB) until gemm2 overwrites it.
    char* ws = (char*)d_ws;
    size_t off = 0;
    unsigned short* Xb = (unsigned short*)(ws + off); off += (size_t)L_SEQ * DMODEL * 2;  // 32MB
    unsigned short* H  = Xb;  // reuse: Xb dead after gemm1, H born in scan_apply
    unsigned short* W1 = (unsigned short*)(ws + off); off += (size_t)DMODEL * DMODEL * 2; // 2MB
    unsigned short* W2 = (unsigned short*)(ws + off); off += (size_t)DMODEL * DMODEL * 2; // 2MB
    float* lam   = (float*)(ws + off); off += 1024 * 4;
    float* lamT  = (float*)(ws + off); off += 1024 * 4;
    float* endRI = (float*)(ws + off); off += (size_t)NCHUNK * 1024 * 4;                  // 1MB
    float* carRI = (float*)(ws + off); off += (size_t)NCHUNK * 1024 * 4;                  // 1MB
    float* Bu = (float*)d_out;

    setup_params<<<1, DSTATE, 0, stream>>>(nu_log, theta_log, lam, lamT);
    pack_w1<<<(DMODEL * DMODEL) / 256, 256, 0, stream>>>(Bre, Bim, gamma_log, W1);
    pack_w2<<<(DMODEL * DMODEL) / 256, 256, 0, stream>>>(Cre, Cim, W2);
    conv_x<<<(L_SEQ * DMODEL / 4) / 256, 256, 0, stream>>>((const float4*)X, (ushort4*)Xb);

    dim3 gg(DMODEL / 128, L_SEQ / 128);   // (8, 128)
    gemm_bf16<0><<<gg, 256, 0, stream>>>(Xb, W1, Bu, nullptr, nullptr);

    scan_local<<<NCHUNK, DSTATE, 0, stream>>>(Bu, lam, endRI);
    scan_carry<<<1, DSTATE, 0, stream>>>(endRI, lamT, carRI);
    scan_apply<<<NCHUNK, DSTATE, 0, stream>>>(Bu, lam, carRI, H);

    gemm_bf16<1><<<gg, 256, 0, stream>>>(H, W2, Y, Dv, X);
}

// Round 3
// 156.445 us; speedup vs baseline: 7.4471x; 1.2951x over previous
//
#include <hip/hip_runtime.h>
#include <math.h>

#define L_SEQ   16384
#define DMODEL  1024
#define NST     512            // complex states
#define CHUNK   128            // == BM of gemm1 tile
#define NCHUNK  (L_SEQ / CHUNK) // 128

typedef float  f32x4 __attribute__((ext_vector_type(4)));
typedef short  s16x8 __attribute__((ext_vector_type(8)));

__device__ __forceinline__ unsigned short f2bf(float f) {     // RNE (cold paths)
    union { float f; unsigned int u; } v; v.f = f;
    unsigned int r = v.u + 0x7fffu + ((v.u >> 16) & 1u);
    return (unsigned short)(r >> 16);
}
__device__ __forceinline__ unsigned short f2bf_fast(float f) { // round-half-up (hot)
    union { float f; unsigned int u; } v; v.f = f;
    return (unsigned short)((v.u + 0x8000u) >> 16);
}
__device__ __forceinline__ float bf2f(unsigned int h16) {      // low 16 bits = bf16
    union { unsigned int u; float f; } v; v.u = h16 << 16; return v.f;
}
__device__ __forceinline__ void mfma16(f32x4& d, s16x8 a, s16x8 b) {
    asm volatile("v_mfma_f32_16x16x32_bf16 %0, %1, %2, %0"
                 : "+v"(d) : "v"(a), "v"(b));
}
__device__ __forceinline__ uint4 pack8(float4 x, float4 y) {
    union { unsigned short u[8]; uint4 v; } t;
    t.u[0] = f2bf_fast(x.x); t.u[1] = f2bf_fast(x.y);
    t.u[2] = f2bf_fast(x.z); t.u[3] = f2bf_fast(x.w);
    t.u[4] = f2bf_fast(y.x); t.u[5] = f2bf_fast(y.y);
    t.u[6] = f2bf_fast(y.z); t.u[7] = f2bf_fast(y.w);
    return t.v;
}

// ---------------- setup: lambda, lambda^64, lambda^128 ----------------
__global__ void setup_params(const float* __restrict__ nu_log,
                             const float* __restrict__ theta_log,
                             float* __restrict__ lam,   // [2][512] re, im
                             float* __restrict__ lamH,  // lambda^64
                             float* __restrict__ lamT) { // lambda^128
    int s = threadIdx.x;
    if (s >= NST) return;
    float mod = expf(-expf(nu_log[s]));
    float th  = expf(theta_log[s]);
    float ar = mod * cosf(th);
    float ai = mod * sinf(th);
    lam[s] = ar; lam[NST + s] = ai;
    float pr = 1.f, pi = 0.f;
    for (int i = 0; i < CHUNK; ++i) {
        float nr = pr * ar - pi * ai;
        float ni = pr * ai + pi * ar;
        pr = nr; pi = ni;
        if (i == 63) { lamH[s] = pr; lamH[NST + s] = pi; }
    }
    lamT[s] = pr; lamT[NST + s] = pi;
}

// ---------------- weight packing (re/im interleaved in N) ----------------
// W1 row 2s   = gamma_s * Bre[s,:],  row 2s+1 = gamma_s * Bim[s,:]
__global__ void pack_w1(const float* __restrict__ Bre, const float* __restrict__ Bim,
                        const float* __restrict__ gamma_log, unsigned short* __restrict__ W1) {
    int idx = blockIdx.x * 256 + threadIdx.x;     // 0 .. 1M-1
    int n = idx >> 10, k = idx & 1023;
    int s = n >> 1;
    float g = expf(gamma_log[s]);
    float v = (n & 1) ? Bim[s * DMODEL + k] : Bre[s * DMODEL + k];
    W1[idx] = f2bf(v * g);
}
// W2[n][2s] = Cre[n][s], W2[n][2s+1] = -Cim[n][s]
__global__ void pack_w2(const float* __restrict__ Cre, const float* __restrict__ Cim,
                        unsigned short* __restrict__ W2) {
    int idx = blockIdx.x * 256 + threadIdx.x;
    int n = idx >> 10, k = idx & 1023;
    int s = k >> 1;
    float v = (k & 1) ? -Cim[n * NST + s] : Cre[n * NST + s];
    W2[idx] = f2bf(v);
}

// ---------- GEMM1 + fused local scan: Bu_loc = scan(X @ W1^T) ----------
// X fp32 (L,1024); W1 bf16 (1024,1024); Bu bf16-pair uint (L,512); ends fp32.
__global__ __launch_bounds__(256)
void gemm1_scan(const float* __restrict__ X, const unsigned short* __restrict__ W1,
                const float* __restrict__ lam,
                unsigned int* __restrict__ Bu, float* __restrict__ ends) {
    const int K = 1024;
    __shared__ __align__(16) unsigned short As[128 * 32];
    __shared__ __align__(16) unsigned short Bs[128 * 32];
    __shared__ __align__(16) unsigned short Ts[128 * 132];  // padded scan tile

    const int tid  = threadIdx.x;
    const int lane = tid & 63;
    const int wave = tid >> 6;
    const int wr   = wave >> 1, wc = wave & 1;

    // XCD-aware swizzle (nwg = 1024, divisible by 8 -> bijective)
    const int lin   = blockIdx.y * gridDim.x + blockIdx.x;
    const int n_new = (lin & 7) * 128 + (lin >> 3);
    const int bx = n_new & 7, by = n_new >> 3;
    const int m0 = by * 128, n0 = bx * 128;

    const int srow = tid >> 2;
    const int skb  = (tid & 3) * 8;

    const float*          Ag0 = X  + (size_t)(m0 + srow) * K + skb;
    const float*          Ag1 = Ag0 + (size_t)64 * K;
    const unsigned short* Bg0 = W1 + (size_t)(n0 + srow) * K + skb;
    const unsigned short* Bg1 = Bg0 + (size_t)64 * K;

    f32x4 acc[4][4] = {};

    float4 a00 = *(const float4*)(Ag0);
    float4 a01 = *(const float4*)(Ag0 + 4);
    float4 a10 = *(const float4*)(Ag1);
    float4 a11 = *(const float4*)(Ag1 + 4);
    uint4  rb0 = *(const uint4*)(Bg0);
    uint4  rb1 = *(const uint4*)(Bg1);

    const int fr = lane & 15;
    const int fk = (lane >> 4) * 8;

    for (int k0 = 0; k0 < K; k0 += 32) {
        __syncthreads();
        *(uint4*)&As[srow * 32 + skb]        = pack8(a00, a01);
        *(uint4*)&As[(64 + srow) * 32 + skb] = pack8(a10, a11);
        *(uint4*)&Bs[srow * 32 + skb]        = rb0;
        *(uint4*)&Bs[(64 + srow) * 32 + skb] = rb1;
        __syncthreads();
        if (k0 + 32 < K) {
            a00 = *(const float4*)(Ag0 + k0 + 32);
            a01 = *(const float4*)(Ag0 + k0 + 36);
            a10 = *(const float4*)(Ag1 + k0 + 32);
            a11 = *(const float4*)(Ag1 + k0 + 36);
            rb0 = *(const uint4*)(Bg0 + k0 + 32);
            rb1 = *(const uint4*)(Bg1 + k0 + 32);
        }
        s16x8 af[4], bfq[4];
        #pragma unroll
        for (int i = 0; i < 4; ++i)
            af[i] = *(const s16x8*)&As[(wr * 64 + i * 16 + fr) * 32 + fk];
        #pragma unroll
        for (int j = 0; j < 4; ++j)
            bfq[j] = *(const s16x8*)&Bs[(wc * 64 + j * 16 + fr) * 32 + fk];
        #pragma unroll
        for (int i = 0; i < 4; ++i)
            #pragma unroll
            for (int j = 0; j < 4; ++j)
                mfma16(acc[i][j], af[i], bfq[j]);
    }

    // stage acc tile to LDS as bf16 (pad 132 -> conflict-free)
    const int crow = (lane >> 4) * 4;
    const int ccol = lane & 15;
    #pragma unroll
    for (int i = 0; i < 4; ++i)
        #pragma unroll
        for (int j = 0; j < 4; ++j)
            #pragma unroll
            for (int r = 0; r < 4; ++r)
                Ts[(wr * 64 + i * 16 + crow + r) * 132 + wc * 64 + j * 16 + ccol]
                    = f2bf_fast(acc[i][j][r]);
    __syncthreads();

    // local scan over the 128 rows; 64 threads = 64 complex states of this block
    if (tid < 64) {
        const int s  = (n0 >> 1) + tid;
        const float lr = lam[s], li = lam[NST + s];
        float hr = 0.f, hi = 0.f;
        size_t gb = (size_t)m0 * NST + s;
        for (int t = 0; t < 128; ++t) {
            unsigned int v = *(const unsigned int*)&Ts[t * 132 + 2 * tid];
            float br = bf2f(v & 0xffffu), bi = bf2f(v >> 16);
            float nr = fmaf(lr, hr, fmaf(-li, hi, br));
            float ni = fmaf(lr, hi, fmaf( li, hr, bi));
            hr = nr; hi = ni;
            Bu[gb + (size_t)t * NST] =
                (unsigned int)f2bf_fast(hr) | ((unsigned int)f2bf_fast(hi) << 16);
        }
        ends[(size_t)(by * NST + s) * 2]     = hr;
        ends[(size_t)(by * NST + s) * 2 + 1] = hi;
    }
}

// ---------------- carry scan across chunks ----------------
__global__ __launch_bounds__(NST)
void scan_carry(const float* __restrict__ ends, const float* __restrict__ lamT,
                float* __restrict__ car) {
    const int s = threadIdx.x;
    const float ar = lamT[s], ai = lamT[NST + s];
    float cr = 0.f, ci = 0.f;
    for (int c = 0; c < NCHUNK; ++c) {
        car[(size_t)(c * NST + s) * 2]     = cr;
        car[(size_t)(c * NST + s) * 2 + 1] = ci;
        float er = ends[(size_t)(c * NST + s) * 2];
        float ei = ends[(size_t)(c * NST + s) * 2 + 1];
        float nr = fmaf(ar, cr, fmaf(-ai, ci, er));
        float ni = fmaf(ar, ci, fmaf( ai, cr, ei));
        cr = nr; ci = ni;
    }
}

// ---------------- apply carries in-place on bf16 Bu ----------------
// grid: 256 blocks = (chunk, half); H[t] = Bu_loc[t] + lambda^{tau+1} * carry
__global__ __launch_bounds__(NST)
void scan_apply(unsigned int* __restrict__ Bu, const float* __restrict__ lam,
                const float* __restrict__ lamH, const float* __restrict__ car) {
    const int c    = blockIdx.x >> 1;
    const int half = blockIdx.x & 1;
    if (c == 0) return;                     // carry is zero
    const int s = threadIdx.x;
    const float lr = lam[s], li = lam[NST + s];
    float pr = car[(size_t)(c * NST + s) * 2];
    float pi = car[(size_t)(c * NST + s) * 2 + 1];
    if (half) {                             // advance by lambda^64
        float hr = lamH[s], hi = lamH[NST + s];
        float nr = pr * hr - pi * hi;
        float ni = pr * hi + pi * hr;
        pr = nr; pi = ni;
    }
    size_t base = ((size_t)c * CHUNK + half * 64) * NST + s;
    #pragma unroll 4
    for (int t = 0; t < 64; ++t) {
        float nr = lr * pr - li * pi;       // lambda^{tau+1} * carry
        float ni = lr * pi + li * pr;
        pr = nr; pi = ni;
        unsigned int v = Bu[base + (size_t)t * NST];
        float hr = bf2f(v & 0xffffu) + pr;
        float hi = bf2f(v >> 16)     + pi;
        Bu[base + (size_t)t * NST] =
            (unsigned int)f2bf_fast(hr) | ((unsigned int)f2bf_fast(hi) << 16);
    }
}

// ---------------- GEMM2: Y = H @ W2^T + D*x ----------------
__global__ __launch_bounds__(256)
void gemm2(const unsigned short* __restrict__ H, const unsigned short* __restrict__ W2,
           float* __restrict__ Y, const float* __restrict__ Dv,
           const float* __restrict__ Xf) {
    const int K = 1024, N = 1024;
    __shared__ __align__(16) unsigned short As[128 * 32];
    __shared__ __align__(16) unsigned short Bs[128 * 32];

    const int tid  = threadIdx.x;
    const int lane = tid & 63;
    const int wave = tid >> 6;
    const int wr   = wave >> 1, wc = wave & 1;

    const int lin   = blockIdx.y * gridDim.x + blockIdx.x;
    const int n_new = (lin & 7) * 128 + (lin >> 3);
    const int bx = n_new & 7, by = n_new >> 3;
    const int m0 = by * 128, n0 = bx * 128;

    const int srow = tid >> 2;
    const int skb  = (tid & 3) * 8;

    const unsigned short* Ag0 = H  + (size_t)(m0 + srow) * K + skb;
    const unsigned short* Ag1 = Ag0 + (size_t)64 * K;
    const unsigned short* Bg0 = W2 + (size_t)(n0 + srow) * K + skb;
    const unsigned short* Bg1 = Bg0 + (size_t)64 * K;

    f32x4 acc[4][4] = {};

    uint4 ra0 = *(const uint4*)Ag0;
    uint4 ra1 = *(const uint4*)Ag1;
    uint4 rb0 = *(const uint4*)Bg0;
    uint4 rb1 = *(const uint4*)Bg1;

    const int fr = lane & 15;
    const int fk = (lane >> 4) * 8;

    for (int k0 = 0; k0 < K; k0 += 32) {
        __syncthreads();
        *(uint4*)&As[srow * 32 + skb]        = ra0;
        *(uint4*)&As[(64 + srow) * 32 + skb] = ra1;
        *(uint4*)&Bs[srow * 32 + skb]        = rb0;
        *(uint4*)&Bs[(64 + srow) * 32 + skb] = rb1;
        __syncthreads();
        if (k0 + 32 < K) {
            ra0 = *(const uint4*)(Ag0 + k0 + 32);
            ra1 = *(const uint4*)(Ag1 + k0 + 32);
            rb0 = *(const uint4*)(Bg0 + k0 + 32);
            rb1 = *(const uint4*)(Bg1 + k0 + 32);
        }
        s16x8 af[4], bfq[4];
        #pragma unroll
        for (int i = 0; i < 4; ++i)
            af[i] = *(const s16x8*)&As[(wr * 64 + i * 16 + fr) * 32 + fk];
        #pragma unroll
        for (int j = 0; j < 4; ++j)
            bfq[j] = *(const s16x8*)&Bs[(wc * 64 + j * 16 + fr) * 32 + fk];
        #pragma unroll
        for (int i = 0; i < 4; ++i)
            #pragma unroll
            for (int j = 0; j < 4; ++j)
                mfma16(acc[i][j], af[i], bfq[j]);
    }

    const int crow = (lane >> 4) * 4;
    const int ccol = lane & 15;
    #pragma unroll
    for (int i = 0; i < 4; ++i) {
        #pragma unroll
        for (int j = 0; j < 4; ++j) {
            const int mbase = m0 + wr * 64 + i * 16 + crow;
            const int n     = n0 + wc * 64 + j * 16 + ccol;
            #pragma unroll
            for (int r = 0; r < 4; ++r) {
                const int m = mbase + r;
                Y[(size_t)m * N + n] = acc[i][j][r] + Dv[n] * Xf[(size_t)m * N + n];
            }
        }
    }
}

extern "C" void kernel_launch(void* const* d_in, const int* in_sizes, int n_in,
                              void* d_out, int out_size, void* d_ws, size_t ws_size,
                              hipStream_t stream) {
    const float* X         = (const float*)d_in[0];
    const float* nu_log    = (const float*)d_in[1];
    const float* theta_log = (const float*)d_in[2];
    const float* gamma_log = (const float*)d_in[3];
    const float* Bre       = (const float*)d_in[4];
    const float* Bim       = (const float*)d_in[5];
    const float* Cre       = (const float*)d_in[6];
    const float* Cim       = (const float*)d_in[7];
    const float* Dv        = (const float*)d_in[8];
    float* Y = (float*)d_out;

    // workspace (~37 MB)
    char* ws = (char*)d_ws;
    size_t off = 0;
    unsigned int*   Bu  = (unsigned int*)(ws + off);   off += (size_t)L_SEQ * NST * 4;   // 32MB (bf16 pairs)
    unsigned short* W1  = (unsigned short*)(ws + off); off += (size_t)DMODEL * DMODEL * 2; // 2MB
    unsigned short* W2  = (unsigned short*)(ws + off); off += (size_t)DMODEL * DMODEL * 2; // 2MB
    float* lam  = (float*)(ws + off); off += 1024 * 4;
    float* lamH = (float*)(ws + off); off += 1024 * 4;
    float* lamT = (float*)(ws + off); off += 1024 * 4;
    float* ends = (float*)(ws + off); off += (size_t)NCHUNK * NST * 2 * 4;  // 512KB
    float* car  = (float*)(ws + off); off += (size_t)NCHUNK * NST * 2 * 4;  // 512KB

    setup_params<<<1, NST, 0, stream>>>(nu_log, theta_log, lam, lamH, lamT);
    pack_w1<<<(DMODEL * DMODEL) / 256, 256, 0, stream>>>(Bre, Bim, gamma_log, W1);
    pack_w2<<<(DMODEL * DMODEL) / 256, 256, 0, stream>>>(Cre, Cim, W2);

    dim3 gg(8, 128);
    gemm1_scan<<<gg, 256, 0, stream>>>(X, W1, lam, Bu, ends);
    scan_carry<<<1, NST, 0, stream>>>(ends, lamT, car);
    scan_apply<<<2 * NCHUNK, NST, 0, stream>>>(Bu, lam, lamH, car);
    gemm2<<<gg, 256, 0, stream>>>((const unsigned short*)Bu, W2, Y, Dv, X);
}